// Round 1
// baseline (246.685 us; speedup 1.0000x reference)
//
#include <hip/hip_runtime.h>
#include <math.h>

namespace {
constexpr int kB  = 64;
constexpr int kT  = 1024;
constexpr int kK  = 512;
constexpr int kC  = 16;        // chunks along T (parallel-scan factor)
constexpr int kL  = kT / kC;   // 64 steps per chunk
constexpr int kKB = 32;        // k-columns per block
constexpr int kBlockThreads = kKB * kC;  // 512
constexpr float kDT = 0.001f;
}

// Chunked linear scan. x_t = A x_{t-1} + B u_t with per-feature 2x2 A.
// Block = 32 k-columns x 16 chunks (512 thr). Each thread scans one 64-step
// chunk from zero state, keeping local outputs in 64 registers (r[i] holds
// u[i] on load, overwritten by local x1 during the scan -> 64 loads in
// flight/wave, zero extra HBM traffic). Chunk end-states exchange via LDS;
// true entry state X_c = prefix over A^L (6 squarings); phase-3 correction
// adds (A^{i+1} X_c)[1] and stores. Exact linear decomposition of the
// serial scan. 1024 blocks -> 8192 waves (16x the serial kernel's 512).
__global__ __launch_bounds__(kBlockThreads, 4) void alpha_scan_chunked(
    const float* __restrict__ in,
    const float* __restrict__ init_level,
    const float* __restrict__ tau,
    float* __restrict__ out)
{
    __shared__ float sx0[kC][kKB];
    __shared__ float sx1[kC][kKB];

    const int tid = threadIdx.x;
    const int kl  = tid & (kKB - 1);     // k within block (fast -> coalesced)
    const int c   = tid >> 5;            // chunk index 0..15
    const int bx  = blockIdx.x;
    const int b   = bx >> 4;             // / (kK/kKB = 16)
    const int k   = ((bx & 15) << 5) + kl;

    // Per-feature coefficients (identical arithmetic to the reference).
    const float tc      = fmaxf(tau[k], 1e-8f);
    const float dt_tau  = kDT / tc;
    const float dt_tau2 = dt_tau / tc;
    const float e       = expf(-dt_tau);

    const float a00 = e * (1.0f - dt_tau);
    const float a01 = e * (-dt_tau2);
    const float a10 = e * kDT;
    const float a11 = e * (1.0f + dt_tau);
    const float b0  = e * dt_tau2;
    const float b1  = 1.0f - e * (1.0f + dt_tau);

    const size_t base = (size_t)b * kT * kK + (size_t)c * kL * kK + k;
    const float* __restrict__ pin  = in  + base;
    float* __restrict__ pout       = out + base;

    // ---- Phase 1: load chunk inputs (64 loads in flight), local scan. ----
    float r[kL];
    #pragma unroll
    for (int i = 0; i < kL; ++i) r[i] = pin[(size_t)i * kK];

    float x0 = 0.0f, x1 = 0.0f;
    #pragma unroll
    for (int i = 0; i < kL; ++i) {
        const float u   = r[i];
        const float nx0 = fmaf(a00, x0, fmaf(a01, x1, b0 * u));
        const float nx1 = fmaf(a10, x0, fmaf(a11, x1, b1 * u));
        x0 = nx0; x1 = nx1;
        r[i] = nx1;                      // local output (zero-init chunk)
    }

    sx0[c][kl] = x0;
    sx1[c][kl] = x1;
    __syncthreads();

    // ---- Phase 2: A^L via repeated squaring (L=64 -> 6 squarings). ----
    float m00 = a00, m01 = a01, m10 = a10, m11 = a11;
    #pragma unroll
    for (int s = 0; s < 6; ++s) {
        const float t00 = fmaf(m00, m00, m01 * m10);
        const float t01 = fmaf(m00, m01, m01 * m11);
        const float t10 = fmaf(m10, m00, m11 * m10);
        const float t11 = fmaf(m10, m01, m11 * m11);
        m00 = t00; m01 = t01; m10 = t10; m11 = t11;
    }

    // Prefix over predecessor chunks: E_j = A^L E_{j-1} + s_j, E_{-1} = x_init.
    float v0 = 0.0f, v1 = init_level[k];
    for (int j = 0; j < c; ++j) {
        const float p0 = fmaf(m00, v0, m01 * v1) + sx0[j][kl];
        const float p1 = fmaf(m10, v0, m11 * v1) + sx1[j][kl];
        v0 = p0; v1 = p1;
    }
    // (v0,v1) = X_c, the true state entering this chunk.

    // ---- Phase 3: correction x_t = local_t + A^{i+1} X_c; store. ----
    #pragma unroll
    for (int i = 0; i < kL; ++i) {
        const float n0 = fmaf(a00, v0, a01 * v1);
        const float n1 = fmaf(a10, v0, a11 * v1);
        v0 = n0; v1 = n1;
        pout[(size_t)i * kK] = r[i] + n1;
    }
}

extern "C" void kernel_launch(void* const* d_in, const int* in_sizes, int n_in,
                              void* d_out, int out_size, void* d_ws, size_t ws_size,
                              hipStream_t stream) {
    const float* in  = (const float*)d_in[0];   // [64,1024,512] fp32
    const float* il  = (const float*)d_in[1];   // [512] fp32
    const float* tau = (const float*)d_in[2];   // [512] fp32
    float* out = (float*)d_out;                 // [64,1024,512] fp32

    dim3 block(kBlockThreads);                        // 512
    dim3 grid(kB * (kK / kKB));                       // 64 * 16 = 1024 blocks
    alpha_scan_chunked<<<grid, block, 0, stream>>>(in, il, tau, out);
}